// Round 2
// baseline (440.451 us; speedup 1.0000x reference)
//
#include <hip/hip_runtime.h>
#include <hip/hip_bf16.h>

// local_NCC_3d v2: warp 4 volumes (trilinear, border-clamped), template=mean,
// 14 stat channels, separable 9^3 zero-padded box sum, cc -> -mean, + grad-L2.
// Fusions vs v1: D-sum folded into the warp/stats kernel (block owns 2 full
// D-lines); cc-combine folded into the H-sum pass (H-sums live in registers).
//
// ws layout: S[14][128^3] f32 (117,440,512 B), then pg2[6144] f64, pcc[1024] f64.

#define NVOX (128*128*128)   // 2^21
#define NGRP 4
#define NCH 14

// ------------------------------------------------ K1: warp + stats + D box-sum
__global__ __launch_bounds__(256) void k_warp_stats_d(
    const float* __restrict__ img, const float* __restrict__ flo,
    float* __restrict__ S)
{
    __shared__ float jt[NGRP][256];     // warped values for the block's 2 D-lines

    int t = threadIdx.x;
    int v = blockIdx.x * 256 + t;
    int d = v & 127;
    int w = (v >> 7) & 127;
    int h = v >> 14;

#pragma unroll
    for (int g = 0; g < NGRP; ++g) {
        const float* f = flo + (size_t)g * 3 * NVOX;
        float ch = fminf(fmaxf(f[v]            + (float)h, 0.f), 127.f);
        float cw = fminf(fmaxf(f[NVOX + v]     + (float)w, 0.f), 127.f);
        float cd = fminf(fmaxf(f[2 * NVOX + v] + (float)d, 0.f), 127.f);
        float h0f = floorf(ch), w0f = floorf(cw), d0f = floorf(cd);
        int h0 = (int)h0f, w0 = (int)w0f, d0 = (int)d0f;
        float fh = ch - h0f, fw = cw - w0f, fd = cd - d0f;
        int h1 = min(h0 + 1, 127), w1 = min(w0 + 1, 127), d1 = min(d0 + 1, 127);
        const float* im = img + (size_t)g * NVOX;
        int b00 = (h0 * 128 + w0) * 128;
        int b01 = (h0 * 128 + w1) * 128;
        int b10 = (h1 * 128 + w0) * 128;
        int b11 = (h1 * 128 + w1) * 128;
        float v000 = im[b00 + d0], v001 = im[b00 + d1];
        float v010 = im[b01 + d0], v011 = im[b01 + d1];
        float v100 = im[b10 + d0], v101 = im[b10 + d1];
        float v110 = im[b11 + d0], v111 = im[b11 + d1];
        float c00 = v000 + fd * (v001 - v000);
        float c01 = v010 + fd * (v011 - v010);
        float c10 = v100 + fd * (v101 - v100);
        float c11 = v110 + fd * (v111 - v110);
        float c0 = c00 + fw * (c01 - c00);
        float c1 = c10 + fw * (c11 - c10);
        jt[g][t] = c0 + fh * (c1 - c0);
    }
    __syncthreads();

    // 9-tap D box-sum of all 14 stat channels, recomputing channel values per
    // tap from the 4 staged j values (box sum is linear in the channel values).
    float s[NCH];
#pragma unroll
    for (int c = 0; c < NCH; ++c) s[c] = 0.f;
    int lbase = t & 128;                // line*128
#pragma unroll
    for (int k = -4; k <= 4; ++k) {
        int q = d + k;
        if ((unsigned)q < 128u) {
            int tq = lbase + q;
            float j0 = jt[0][tq], j1 = jt[1][tq], j2 = jt[2][tq], j3 = jt[3][tq];
            float tm = 0.25f * (j0 + j1 + j2 + j3);
            s[0] += tm;       s[1] += tm * tm;
            s[2] += j0;  s[3] += j0 * j0;  s[4]  += tm * j0;
            s[5] += j1;  s[6] += j1 * j1;  s[7]  += tm * j1;
            s[8] += j2;  s[9] += j2 * j2;  s[10] += tm * j2;
            s[11] += j3; s[12] += j3 * j3; s[13] += tm * j3;
        }
    }
#pragma unroll
    for (int c = 0; c < NCH; ++c) S[(size_t)c * NVOX + v] = s[c];
}

// ------------------------------------------------ g2 regularizer
__global__ __launch_bounds__(256) void k_g2(const float* __restrict__ flo,
                                            double* __restrict__ pg2)
{
    const int stride = 6144 * 256;
    int base = blockIdx.x * 256 + threadIdx.x;
    float s = 0.f;
#pragma unroll
    for (int k = 0; k < 16; ++k) {
        int i = base + k * stride;          // < 12*NVOX
        int v = i & (NVOX - 1);
        int c = i >> 21;
        const float* f = flo + (size_t)c * NVOX;
        float x = f[v];
        int d = v & 127, w = (v >> 7) & 127, h = v >> 14;
        if (h < 127) { float t = f[v + 128 * 128] - x; s += t * t; }
        if (w < 127) { float t = f[v + 128] - x;       s += t * t; }
        if (d < 127) { float t = f[v + 1] - x;         s += t * t; }
    }
    double val = (double)s;
    for (int off = 32; off; off >>= 1) val += __shfl_down(val, off, 64);
    __shared__ double wsum[4];
    int lane = threadIdx.x & 63, wid = threadIdx.x >> 6;
    if (lane == 0) wsum[wid] = val;
    __syncthreads();
    if (threadIdx.x == 0) pg2[blockIdx.x] = wsum[0] + wsum[1] + wsum[2] + wsum[3];
}

// ------------------------------------------------ box-sum along W (in-place)
__global__ __launch_bounds__(256) void k_sum_w(float* __restrict__ S)
{
    __shared__ float tile[128 * 64];                // [w][dd]
    int bid = blockIdx.x;
    int half = bid & 1;
    int chh = bid >> 1;                             // c*128 + h
    size_t base = (size_t)chh * (128 * 128) + half * 64;
#pragma unroll
    for (int it = 0; it < 8; ++it) {
        int idx4 = it * 256 + threadIdx.x;          // [0, 2048)
        int w = idx4 >> 4, dq = idx4 & 15;
        float4 vv = *(const float4*)(S + base + (size_t)w * 128 + dq * 4);
        *(float4*)(tile + w * 64 + dq * 4) = vv;
    }
    __syncthreads();
    int dd = threadIdx.x & 63;
    int wg = threadIdx.x >> 6;                      // 0..3
    for (int wi = 0; wi < 32; ++wi) {
        int w = wg * 32 + wi;
        float s = 0.f;
#pragma unroll
        for (int k = -4; k <= 4; ++k) {
            int q = w + k;
            if (q >= 0 && q < 128) s += tile[q * 64 + dd];
        }
        S[base + (size_t)w * 128 + dd] = s;
    }
}

// ------------------------------------------------ H box-sum + cc combine (fused)
#define LOAD_HSUM(c, acc)                                                      \
    do {                                                                       \
        const float* cp = S + (size_t)(c) * NVOX + sbase;                      \
        _Pragma("unroll")                                                      \
        for (int it = 0; it < 2; ++it) {                                       \
            int idx4 = it * 256 + t;           /* [0,512) */                   \
            int hh = idx4 >> 2, dq = idx4 & 3;                                 \
            float4 vv = *(const float4*)(cp + (size_t)hh * 16384 + dq * 4);    \
            int la = hh * 17 + dq * 4;                                         \
            tile[la] = vv.x; tile[la + 1] = vv.y;                              \
            tile[la + 2] = vv.z; tile[la + 3] = vv.w;                          \
        }                                                                      \
        __syncthreads();                                                       \
        _Pragma("unroll")                                                      \
        for (int j8 = 0; j8 < 8; ++j8) {                                       \
            int vox = t + 256 * j8;                                            \
            int hh = vox >> 4, dd = vox & 15;                                  \
            float sum = 0.f;                                                   \
            _Pragma("unroll")                                                  \
            for (int k = -4; k <= 4; ++k) {                                    \
                int q = hh + k;                                                \
                if ((unsigned)q < 128u) sum += tile[q * 17 + dd];              \
            }                                                                  \
            acc[j8] = sum;                                                     \
        }                                                                      \
        __syncthreads();                                                       \
    } while (0)

__global__ __launch_bounds__(256) void k_sum_h_cc(const float* __restrict__ S,
                                                  double* __restrict__ pcc)
{
    __shared__ float tile[128 * 17];                // 8.7 KB
    int t = threadIdx.x;
    int w = blockIdx.x >> 3;
    int ddb = blockIdx.x & 7;
    size_t sbase = (size_t)w * 128 + (size_t)ddb * 16;  // + c*NVOX + h*16384 + dd

    float Iacc[8], I2acc[8], Ja[8], J2a[8], IJa[8];
    float lsum = 0.f;
    const float inv = 1.0f / 729.0f;

    LOAD_HSUM(0, Iacc);
    LOAD_HSUM(1, I2acc);
    for (int g = 0; g < NGRP; ++g) {
        LOAD_HSUM(2 + 3 * g, Ja);
        LOAD_HSUM(3 + 3 * g, J2a);
        LOAD_HSUM(4 + 3 * g, IJa);
#pragma unroll
        for (int j8 = 0; j8 < 8; ++j8) {
            float cross = IJa[j8] - Ja[j8] * Iacc[j8] * inv;
            float Ivar  = I2acc[j8] - Iacc[j8] * Iacc[j8] * inv;
            float Jvar  = J2a[j8] - Ja[j8] * Ja[j8] * inv;
            lsum += cross * cross / (Ivar * Jvar + 1e-5f);
        }
    }

    double val = (double)lsum;
    for (int off = 32; off; off >>= 1) val += __shfl_down(val, off, 64);
    __shared__ double wsum[4];
    int lane = t & 63, wid = t >> 6;
    if (lane == 0) wsum[wid] = val;
    __syncthreads();
    if (t == 0) pcc[blockIdx.x] = wsum[0] + wsum[1] + wsum[2] + wsum[3];
}

// ------------------------------------------------ finalize
__global__ __launch_bounds__(256) void k_finalize(const double* __restrict__ pg2,
                                                  const double* __restrict__ pcc,
                                                  float* __restrict__ out)
{
    double s_cc = 0.0, s_g2 = 0.0;
    for (int i = threadIdx.x; i < 1024; i += 256) s_cc += pcc[i];
    for (int i = threadIdx.x; i < 6144; i += 256) s_g2 += pg2[i];
    for (int off = 32; off; off >>= 1) {
        s_cc += __shfl_down(s_cc, off, 64);
        s_g2 += __shfl_down(s_g2, off, 64);
    }
    __shared__ double a[4], b[4];
    int lane = threadIdx.x & 63, wid = threadIdx.x >> 6;
    if (lane == 0) { a[wid] = s_cc; b[wid] = s_g2; }
    __syncthreads();
    if (threadIdx.x == 0) {
        double cc_sum = a[0] + a[1] + a[2] + a[3];
        double g2_sum = b[0] + b[1] + b[2] + b[3];
        double lncc = -cc_sum / (4.0 * (double)NVOX);
        double g2 = g2_sum / (3.0 * 12.0 * 127.0 * 128.0 * 128.0);
        out[0] = (float)(lncc + g2);
    }
}

extern "C" void kernel_launch(void* const* d_in, const int* in_sizes, int n_in,
                              void* d_out, int out_size, void* d_ws, size_t ws_size,
                              hipStream_t stream)
{
    const float* img = (const float*)d_in[0];   // [4][1][128^3]
    const float* flo = (const float*)d_in[1];   // [4][3][128^3]
    float* out = (float*)d_out;

    float* S = (float*)d_ws;                                       // 14*NVOX f32
    double* pg2 = (double*)((char*)d_ws + (size_t)NCH * NVOX * 4); // 6144 f64
    double* pcc = pg2 + 6144;                                      // 1024 f64

    k_warp_stats_d<<<NVOX / 256, 256, 0, stream>>>(img, flo, S);   // 8192 blocks
    k_g2<<<6144, 256, 0, stream>>>(flo, pg2);
    k_sum_w<<<NCH * 128 * 2, 256, 0, stream>>>(S);                 // 3584 blocks
    k_sum_h_cc<<<1024, 256, 0, stream>>>(S, pcc);                  // 128w * 8ddb
    k_finalize<<<1, 256, 0, stream>>>(pg2, pcc, out);
}

// Round 3
// 376.513 us; speedup vs baseline: 1.1698x; 1.1698x over previous
//
#include <hip/hip_runtime.h>
#include <hip/hip_bf16.h>

// local_NCC_3d v3.
// K1: warp (trilinear, border-clamped) + 14 stat channels + 9-tap D box-sum
//     + fused grad-L2 on flows (flows are already resident).
// K2: W box-sum in-place (float4 loads/stores, b128 LDS taps).
// K3: H box-sum + cc combine fused, h-split x2 for MLP.
// K4: finalize partials.
// ws: S[14][128^3] f32, pg2[8192] f64, pcc[2048] f64.

#define NVOX (128*128*128)   // 2^21
#define NGRP 4
#define NCH 14

// ------------------------------------------------ K1: warp + stats + D-sum + g2
__global__ __launch_bounds__(256, 3) void k_warp_stats_d(
    const float* __restrict__ img, const float* __restrict__ flo,
    float* __restrict__ S, double* __restrict__ pg2)
{
    __shared__ float jt[NGRP][256];     // warped values for the block's 2 D-lines
    int t = threadIdx.x;
    int v = blockIdx.x * 256 + t;
    int d = v & 127;
    int w = (v >> 7) & 127;
    int h = v >> 14;
    float g2s = 0.f;

#pragma unroll
    for (int gb = 0; gb < 2; ++gb) {    // 2 batches of 2 groups: 16 gathers in flight
        float cv[2][8], tfh[2], tfw[2], tfd[2];
#pragma unroll
        for (int gi = 0; gi < 2; ++gi) {
            int g = gb * 2 + gi;
            const float* f = flo + (size_t)g * 3 * NVOX;
            float fx = f[v], fy = f[NVOX + v], fz = f[2 * NVOX + v];
            // grad-L2 (masked coalesced diffs; h/w/d neighbor streams are L1/L2-warm)
            if (h < 127) {
                float a = f[v + 16384] - fx;
                float b = f[NVOX + v + 16384] - fy;
                float c = f[2 * NVOX + v + 16384] - fz;
                g2s += a * a + b * b + c * c;
            }
            if (w < 127) {
                float a = f[v + 128] - fx;
                float b = f[NVOX + v + 128] - fy;
                float c = f[2 * NVOX + v + 128] - fz;
                g2s += a * a + b * b + c * c;
            }
            if (d < 127) {
                float a = f[v + 1] - fx;
                float b = f[NVOX + v + 1] - fy;
                float c = f[2 * NVOX + v + 1] - fz;
                g2s += a * a + b * b + c * c;
            }
            // warp coords
            float ch = fminf(fmaxf(fx + (float)h, 0.f), 127.f);
            float cw = fminf(fmaxf(fy + (float)w, 0.f), 127.f);
            float cd = fminf(fmaxf(fz + (float)d, 0.f), 127.f);
            float h0f = floorf(ch), w0f = floorf(cw), d0f = floorf(cd);
            int h0 = (int)h0f, w0 = (int)w0f, d0 = (int)d0f;
            tfh[gi] = ch - h0f; tfw[gi] = cw - w0f; tfd[gi] = cd - d0f;
            int h1 = min(h0 + 1, 127), w1 = min(w0 + 1, 127), d1 = min(d0 + 1, 127);
            const float* im = img + (size_t)g * NVOX;
            int b00 = (h0 * 128 + w0) * 128;
            int b01 = (h0 * 128 + w1) * 128;
            int b10 = (h1 * 128 + w0) * 128;
            int b11 = (h1 * 128 + w1) * 128;
            cv[gi][0] = im[b00 + d0]; cv[gi][1] = im[b00 + d1];
            cv[gi][2] = im[b01 + d0]; cv[gi][3] = im[b01 + d1];
            cv[gi][4] = im[b10 + d0]; cv[gi][5] = im[b10 + d1];
            cv[gi][6] = im[b11 + d0]; cv[gi][7] = im[b11 + d1];
        }
#pragma unroll
        for (int gi = 0; gi < 2; ++gi) {
            float fd_ = tfd[gi], fw_ = tfw[gi], fh_ = tfh[gi];
            float c00 = cv[gi][0] + fd_ * (cv[gi][1] - cv[gi][0]);
            float c01 = cv[gi][2] + fd_ * (cv[gi][3] - cv[gi][2]);
            float c10 = cv[gi][4] + fd_ * (cv[gi][5] - cv[gi][4]);
            float c11 = cv[gi][6] + fd_ * (cv[gi][7] - cv[gi][6]);
            float c0 = c00 + fw_ * (c01 - c00);
            float c1 = c10 + fw_ * (c11 - c10);
            jt[gb * 2 + gi][t] = c0 + fh_ * (c1 - c0);
        }
    }
    __syncthreads();

    // 9-tap D box-sum of 14 product channels from staged j values
    float s[NCH];
#pragma unroll
    for (int c = 0; c < NCH; ++c) s[c] = 0.f;
    int lbase = t & 128;                // line*128
#pragma unroll
    for (int k = -4; k <= 4; ++k) {
        int q = d + k;
        if ((unsigned)q < 128u) {
            int tq = lbase + q;
            float j0 = jt[0][tq], j1 = jt[1][tq], j2 = jt[2][tq], j3 = jt[3][tq];
            float tm = 0.25f * (j0 + j1 + j2 + j3);
            s[0] += tm;       s[1] += tm * tm;
            s[2] += j0;  s[3] += j0 * j0;  s[4]  += tm * j0;
            s[5] += j1;  s[6] += j1 * j1;  s[7]  += tm * j1;
            s[8] += j2;  s[9] += j2 * j2;  s[10] += tm * j2;
            s[11] += j3; s[12] += j3 * j3; s[13] += tm * j3;
        }
    }
#pragma unroll
    for (int c = 0; c < NCH; ++c) S[(size_t)c * NVOX + v] = s[c];

    // g2 block reduction
    double val = (double)g2s;
    for (int off = 32; off; off >>= 1) val += __shfl_down(val, off, 64);
    __shared__ double wsum[4];
    int lane = t & 63, wid = t >> 6;
    if (lane == 0) wsum[wid] = val;
    __syncthreads();
    if (t == 0) pg2[blockIdx.x] = wsum[0] + wsum[1] + wsum[2] + wsum[3];
}

// ------------------------------------------------ K2: W box-sum (in-place, vectorized)
__global__ __launch_bounds__(256) void k_sum_w(float* __restrict__ S)
{
    __shared__ float tile[128 * 64];                // [w][dd]
    int bid = blockIdx.x;
    int half = bid & 1;
    int chh = bid >> 1;                             // c*128 + h
    size_t base = (size_t)chh * 16384 + half * 64;
#pragma unroll
    for (int it = 0; it < 8; ++it) {
        int idx4 = it * 256 + threadIdx.x;          // [0, 2048)
        int w = idx4 >> 4, dq = idx4 & 15;
        *(float4*)(tile + w * 64 + dq * 4) =
            *(const float4*)(S + base + (size_t)w * 128 + dq * 4);
    }
    __syncthreads();
    int dq = threadIdx.x & 15;                      // dd4 = dq*4
    int wq = threadIdx.x >> 4;                      // 0..15, 8 w each
#pragma unroll
    for (int wi = 0; wi < 8; ++wi) {
        int w = wq * 8 + wi;
        float4 s = make_float4(0.f, 0.f, 0.f, 0.f);
#pragma unroll
        for (int k = -4; k <= 4; ++k) {
            int q = w + k;
            if ((unsigned)q < 128u) {
                float4 tv = *(const float4*)(tile + q * 64 + dq * 4);
                s.x += tv.x; s.y += tv.y; s.z += tv.z; s.w += tv.w;
            }
        }
        *(float4*)(S + base + (size_t)w * 128 + dq * 4) = s;
    }
}

// ------------------------------------------------ K3: H box-sum + cc (h-split x2)
#define LOAD_HSUM(c, acc)                                                      \
    do {                                                                       \
        const float* cp = S + (size_t)(c) * NVOX + sbase;                      \
        _Pragma("unroll")                                                      \
        for (int it = 0; it < 2; ++it) {                                       \
            int idx4 = it * 256 + t;                                           \
            if (idx4 < 272) {                   /* 68 rows x 4 quads */        \
                int hh = idx4 >> 2, dq = idx4 & 3;                             \
                float4 vv = *(const float4*)(cp + (size_t)(r0 + hh) * 16384 + dq * 4); \
                int la = hh * 17 + dq * 4;                                     \
                tile[la] = vv.x; tile[la + 1] = vv.y;                          \
                tile[la + 2] = vv.z; tile[la + 3] = vv.w;                      \
            }                                                                  \
        }                                                                      \
        __syncthreads();                                                       \
        _Pragma("unroll")                                                      \
        for (int j4 = 0; j4 < 4; ++j4) {                                       \
            int vox = t + 256 * j4;                                            \
            int ho = vox >> 4, dd = vox & 15;                                  \
            int hg = hbase + ho;                                               \
            float sum = 0.f;                                                   \
            _Pragma("unroll")                                                  \
            for (int k = -4; k <= 4; ++k) {                                    \
                int q = hg + k;                                                \
                if ((unsigned)q < 128u) sum += tile[(q - r0) * 17 + dd];       \
            }                                                                  \
            acc[j4] = sum;                                                     \
        }                                                                      \
        __syncthreads();                                                       \
    } while (0)

__global__ __launch_bounds__(256) void k_sum_h_cc(const float* __restrict__ S,
                                                  double* __restrict__ pcc)
{
    __shared__ float tile[68 * 17];                 // 4.6 KB
    int t = threadIdx.x;
    int bid = blockIdx.x;                           // 128 w * 8 ddb * 2 hs
    int hs = bid & 1;
    int ddb = (bid >> 1) & 7;
    int w = bid >> 4;
    int r0 = hs ? 60 : 0;                           // first staged row
    int hbase = hs * 64;                            // first output row
    size_t sbase = (size_t)w * 128 + (size_t)ddb * 16;

    float Iacc[4], I2acc[4], Ja[4], J2a[4], IJa[4];
    float lsum = 0.f;
    const float inv = 1.0f / 729.0f;

    LOAD_HSUM(0, Iacc);
    LOAD_HSUM(1, I2acc);
    for (int g = 0; g < NGRP; ++g) {
        LOAD_HSUM(2 + 3 * g, Ja);
        LOAD_HSUM(3 + 3 * g, J2a);
        LOAD_HSUM(4 + 3 * g, IJa);
#pragma unroll
        for (int j4 = 0; j4 < 4; ++j4) {
            float cross = IJa[j4] - Ja[j4] * Iacc[j4] * inv;
            float Ivar  = I2acc[j4] - Iacc[j4] * Iacc[j4] * inv;
            float Jvar  = J2a[j4] - Ja[j4] * Ja[j4] * inv;
            lsum += cross * cross / (Ivar * Jvar + 1e-5f);
        }
    }

    double val = (double)lsum;
    for (int off = 32; off; off >>= 1) val += __shfl_down(val, off, 64);
    __shared__ double wsum[4];
    int lane = t & 63, wid = t >> 6;
    if (lane == 0) wsum[wid] = val;
    __syncthreads();
    if (t == 0) pcc[bid] = wsum[0] + wsum[1] + wsum[2] + wsum[3];
}

// ------------------------------------------------ K4: finalize
__global__ __launch_bounds__(256) void k_finalize(const double* __restrict__ pg2,
                                                  const double* __restrict__ pcc,
                                                  float* __restrict__ out)
{
    double s_cc = 0.0, s_g2 = 0.0;
    for (int i = threadIdx.x; i < 2048; i += 256) s_cc += pcc[i];
    for (int i = threadIdx.x; i < 8192; i += 256) s_g2 += pg2[i];
    for (int off = 32; off; off >>= 1) {
        s_cc += __shfl_down(s_cc, off, 64);
        s_g2 += __shfl_down(s_g2, off, 64);
    }
    __shared__ double a[4], b[4];
    int lane = threadIdx.x & 63, wid = threadIdx.x >> 6;
    if (lane == 0) { a[wid] = s_cc; b[wid] = s_g2; }
    __syncthreads();
    if (threadIdx.x == 0) {
        double cc_sum = a[0] + a[1] + a[2] + a[3];
        double g2_sum = b[0] + b[1] + b[2] + b[3];
        double lncc = -cc_sum / (4.0 * (double)NVOX);
        double g2 = g2_sum / (3.0 * 12.0 * 127.0 * 128.0 * 128.0);
        out[0] = (float)(lncc + g2);
    }
}

extern "C" void kernel_launch(void* const* d_in, const int* in_sizes, int n_in,
                              void* d_out, int out_size, void* d_ws, size_t ws_size,
                              hipStream_t stream)
{
    const float* img = (const float*)d_in[0];   // [4][1][128^3]
    const float* flo = (const float*)d_in[1];   // [4][3][128^3]
    float* out = (float*)d_out;

    float* S = (float*)d_ws;                                       // 14*NVOX f32
    double* pg2 = (double*)((char*)d_ws + (size_t)NCH * NVOX * 4); // 8192 f64
    double* pcc = pg2 + 8192;                                      // 2048 f64

    k_warp_stats_d<<<NVOX / 256, 256, 0, stream>>>(img, flo, S, pg2); // 8192 blocks
    k_sum_w<<<NCH * 128 * 2, 256, 0, stream>>>(S);                    // 3584 blocks
    k_sum_h_cc<<<2048, 256, 0, stream>>>(S, pcc);                     // 128w*8ddb*2hs
    k_finalize<<<1, 256, 0, stream>>>(pg2, pcc, out);
}